// Round 7
// baseline (983.952 us; speedup 1.0000x reference)
//
#include <hip/hip_runtime.h>
#include <hip/hip_bf16.h>
#include <math.h>

#define N_BATCH 8
#define WDIM 64
#define TDIM 8192
#define KBINS 2048
#define NROWS (N_BATCH * TDIM)          // 65536
#define XSIZE (N_BATCH * WDIM * TDIM)   // 4194304
#define XL_OFF 0
#define XD_OFF NROWS
#define SCAL_OFF (NROWS + XSIZE)

#define MT 128                          // rows per block (vq)
#define XST 72                          // bf16 LDS x row stride
#define TAU 0.5f                        // validated in round 4 (hi-only bf16)
#define MAXFLAG 16384
#define RROWS 8                         // rows per recheck block

// ws layout (bytes):
//   0     : double wsd[4]
//   64    : float  k2[KBINS]           (np-bit-exact)
//   8320  : int    flag_cnt
//   8384  : int    flags[MAXFLAG]      (64 KB)
//   73984 : short  khi[KBINS*64]       (256 KB bf16)
#define WS_K2_OFF   64
#define WS_CNT_OFF  8320
#define WS_FLAG_OFF 8384
#define WS_KHI_OFF  73984

typedef __attribute__((ext_vector_type(8))) short bf16x8;
typedef __attribute__((ext_vector_type(4))) float f32x4;

static __device__ __forceinline__ short f2bf(float v) {
  __hip_bfloat16 b = __float2bfloat16(v);
  return *reinterpret_cast<short*>(&b);
}

// prep: init ws + np-bit-exact k2 + bf16 codebook, all coalesced via LDS.
__global__ void prep_kernel(const float* __restrict__ kg, float* __restrict__ k2,
                            short* __restrict__ khi,
                            double* __restrict__ wsd, int* __restrict__ cnt) {
  __shared__ float skc[128 * 65];
  const int tid = threadIdx.x;
  const int c0 = blockIdx.x * 128;
  if (blockIdx.x == 0) {
    if (tid < 4) wsd[tid] = 0.0;
    if (tid == 4) *cnt = 0;
  }
  const float4* g4 = (const float4*)(kg + (size_t)c0 * WDIM);
#pragma unroll
  for (int i = 0; i < 8; ++i) {
    int idx = i * 256 + tid;
    int code = idx >> 4, w = (idx & 15) * 4;
    *(float4*)&skc[code * 65 + w] = g4[idx];
  }
  __syncthreads();
  if (tid < 128) {   // np-bit-exact k2 (8-accumulator pairwise)
    const float* kr = &skc[tid * 65];
    float r[8];
#pragma unroll
    for (int l = 0; l < 8; ++l) r[l] = __fmul_rn(kr[l], kr[l]);
    for (int i = 8; i < WDIM; i += 8) {
#pragma unroll
      for (int l = 0; l < 8; ++l)
        r[l] = __fadd_rn(r[l], __fmul_rn(kr[i + l], kr[i + l]));
    }
    k2[c0 + tid] = __fadd_rn(__fadd_rn(__fadd_rn(r[0], r[1]), __fadd_rn(r[2], r[3])),
                             __fadd_rn(__fadd_rn(r[4], r[5]), __fadd_rn(r[6], r[7])));
  }
#pragma unroll
  for (int i = 0; i < 32; ++i) {
    int idx = i * 256 + tid;
    int code = idx >> 6, w = idx & 63;
    khi[(size_t)(c0 + code) * WDIM + w] = f2bf(skc[code * 65 + w]);
  }
}

// main: bf16 MFMA distance scan, B direct from global (L2), depth-1 pipelined.
__launch_bounds__(256, 4)
__global__ void vq_mfma(const float* __restrict__ x,
                        const float* __restrict__ kg,
                        const float* __restrict__ k2g,
                        const short* __restrict__ khi,
                        float* __restrict__ out,
                        double* __restrict__ wsd,
                        int* __restrict__ flag_cnt,
                        int* __restrict__ flags) {
  __shared__ __align__(16) char smem[38912];
  short* sxh  = (short*)smem;              // [MT][XST] bf16        (18432 B)
  float* sx2  = (float*)(smem + 36864);    // per-row x2            (512 B)
  float* sPair= (float*)(smem + 37376);    // x2 partials           (1024 B)
  int*   sIdx = (int*)  (smem + 38400);    // chosen code per row   (512 B)
  float* kd   = (float*)smem;              // epilogue [MT][68] f32 (reuses sxh)

  const int tid  = threadIdx.x;
  const int row0 = blockIdx.x * MT;
  const int n    = row0 >> 13;
  const int t0   = row0 & (TDIM - 1);

  // ---- stage x tile -> bf16; fp32 partials ----
  const int r  = tid & 127;
  const int wh = tid >> 7;
  float x2p = 0.f, sxp = 0.f;
  const float* xb = x + (size_t)n * WDIM * TDIM + t0 + r;
#pragma unroll 8
  for (int i = 0; i < 32; ++i) {
    int w = 2 * i + wh;
    float v = xb[(size_t)w * TDIM];
    x2p = fmaf(v, v, x2p);
    sxp += v;
    sxh[r * XST + w] = f2bf(v);
  }
  sPair[tid] = x2p;
  __syncthreads();
  if (tid < MT) sx2[tid] = sPair[tid] + sPair[tid + 128];
  __syncthreads();

  // ---- A fragments (registers for the whole sweep) ----
  const int wave = tid >> 6;
  const int lane = tid & 63;
  const int lcol = lane & 15;
  const int quad = lane >> 4;
  const int rA0 = wave * 32 + lcol;
  const int rA1 = wave * 32 + 16 + lcol;
  bf16x8 a0h0 = *(const bf16x8*)&sxh[rA0 * XST + 0  + quad * 8];
  bf16x8 a0h1 = *(const bf16x8*)&sxh[rA0 * XST + 32 + quad * 8];
  bf16x8 a1h0 = *(const bf16x8*)&sxh[rA1 * XST + 0  + quad * 8];
  bf16x8 a1h1 = *(const bf16x8*)&sxh[rA1 * XST + 32 + quad * 8];

  float bd[8], b2[8];
  int   bi[8];
#pragma unroll
  for (int i = 0; i < 8; ++i) { bd[i] = 3.0e38f; b2[i] = 3.0e38f; bi[i] = 0; }

  // ---- pipelined sweep: 16 codes/tile, depth-1 register double buffer ----
  const short* kbase = khi + (size_t)(lcol * WDIM + quad * 8);
  const float* k2b   = k2g + lcol;

  bf16x8 pb0, pb1, qb0, qb1;
  float  pk2, qk2;
  pb0 = *(const bf16x8*)&kbase[0];
  pb1 = *(const bf16x8*)&kbase[32];
  pk2 = k2b[0];

#define VQ_STEP(B0, B1, KK, CB)                                              \
  {                                                                          \
    f32x4 acc0 = {0.f, 0.f, 0.f, 0.f};                                       \
    f32x4 acc1 = {0.f, 0.f, 0.f, 0.f};                                       \
    acc0 = __builtin_amdgcn_mfma_f32_16x16x32_bf16(a0h0, B0, acc0, 0, 0, 0); \
    acc1 = __builtin_amdgcn_mfma_f32_16x16x32_bf16(a1h0, B0, acc1, 0, 0, 0); \
    acc0 = __builtin_amdgcn_mfma_f32_16x16x32_bf16(a0h1, B1, acc0, 0, 0, 0); \
    acc1 = __builtin_amdgcn_mfma_f32_16x16x32_bf16(a1h1, B1, acc1, 0, 0, 0); \
    const int code = (CB) + lcol;                                            \
    _Pragma("unroll")                                                        \
    for (int i = 0; i < 4; ++i) {                                            \
      float d0 = fmaf(-2.f, acc0[i], KK);                                    \
      float nb2a = fminf(b2[i], fmaxf(bd[i], d0));                           \
      bool lt0 = d0 < bd[i];                                                 \
      bd[i] = lt0 ? d0 : bd[i];                                              \
      bi[i] = lt0 ? code : bi[i];                                            \
      b2[i] = nb2a;                                                          \
      float d1 = fmaf(-2.f, acc1[i], KK);                                    \
      float nb2b = fminf(b2[4 + i], fmaxf(bd[4 + i], d1));                   \
      bool lt1 = d1 < bd[4 + i];                                             \
      bd[4 + i] = lt1 ? d1 : bd[4 + i];                                      \
      bi[4 + i] = lt1 ? code : bi[4 + i];                                    \
      b2[4 + i] = nb2b;                                                      \
    }                                                                        \
  }

  for (int cb = 0; cb < KBINS; cb += 32) {
    {
      const short* p = kbase + (size_t)(cb + 16) * WDIM;
      qb0 = *(const bf16x8*)&p[0];
      qb1 = *(const bf16x8*)&p[32];
      qk2 = k2b[cb + 16];
    }
    VQ_STEP(pb0, pb1, pk2, cb)
    {
      const short* p = kbase + (size_t)((cb + 32) & (KBINS - 1)) * WDIM;
      pb0 = *(const bf16x8*)&p[0];
      pb1 = *(const bf16x8*)&p[32];
      pk2 = k2b[(cb + 32) & (KBINS - 1)];
    }
    VQ_STEP(qb0, qb1, qk2, cb + 16)
  }
#undef VQ_STEP

  // ---- reduce across the 16 col-classes ----
#pragma unroll
  for (int m = 1; m < 16; m <<= 1) {
#pragma unroll
    for (int i = 0; i < 8; ++i) {
      float od  = __shfl_xor(bd[i], m, 64);
      float od2 = __shfl_xor(b2[i], m, 64);
      int   oi  = __shfl_xor(bi[i], m, 64);
      float nb2 = fminf(fminf(b2[i], od2), fmaxf(bd[i], od));
      bool take = (od < bd[i]) || (od == bd[i] && oi < bi[i]);
      bd[i] = take ? od : bd[i];
      bi[i] = take ? oi : bi[i];
      b2[i] = nb2;
    }
  }

  float fit_p = 0.f;
  if (lcol == 0) {
#pragma unroll
    for (int i = 0; i < 8; ++i) {
      int s = i >> 2, ii = i & 3;
      int rloc = wave * 32 + s * 16 + quad * 4 + ii;
      int rowg = row0 + rloc;
      out[XL_OFF + rowg] = (float)bi[i];
      sIdx[rloc] = bi[i];
      fit_p += bd[i] + sx2[rloc];
      if (b2[i] - bd[i] < TAU) {
        int slot = atomicAdd(flag_cnt, 1);
        if (slot < MAXFLAG) flags[slot] = rowg;
      }
    }
  }
  __syncthreads();

  // ---- gather chosen code rows (fp32) into LDS ----
  {
    int rr = tid >> 1, half = tid & 1;
    const float4* kr4 = (const float4*)(kg + (size_t)sIdx[rr] * WDIM + half * 32);
    float4* dst = (float4*)&kd[rr * 68 + half * 32];
#pragma unroll
    for (int j = 0; j < 8; ++j) dst[j] = kr4[j];
  }
  __syncthreads();

  // ---- x_d transposed write + commit ----
  float commit_p = 0.f;
  float* xdb = out + XD_OFF + (size_t)n * WDIM * TDIM + t0 + r;
#pragma unroll 8
  for (int i = 0; i < 32; ++i) {
    int w = 2 * i + wh;
    float xvv = xb[(size_t)w * TDIM];
    float kvv = kd[r * 68 + w];
    float df = kvv - xvv;
    commit_p = fmaf(df, df, commit_p);
    xdb[(size_t)w * TDIM] = kvv;
  }

  // ---- block scalar reduction -> global atomics ----
  float v0 = sxp, v1 = x2p, v2 = commit_p, v3 = fit_p;
#pragma unroll
  for (int off = 32; off > 0; off >>= 1) {
    v0 += __shfl_down(v0, off, 64);
    v1 += __shfl_down(v1, off, 64);
    v2 += __shfl_down(v2, off, 64);
    v3 += __shfl_down(v3, off, 64);
  }
  if (lane == 0) {
    atomicAdd(&wsd[0], (double)v0);
    atomicAdd(&wsd[1], (double)v1);
    atomicAdd(&wsd[2], (double)v2);
    atomicAdd(&wsd[3], (double)v3);
  }
}

// numpy-bit-exact fp32 re-scan: 8 flagged rows per block.
// x rows broadcast from LDS (same-address -> free); k read once per block,
// 8 sequential FMA chains per k element (np-exact per (row,code)).
__launch_bounds__(256, 4)
__global__ void recheck_np(const float* __restrict__ x,
                           const float* __restrict__ kg,
                           const float* __restrict__ k2g,
                           const int* __restrict__ flag_cnt,
                           const int* __restrict__ flags,
                           float* __restrict__ out) {
  __shared__ float sxr[RROWS][WDIM];
  __shared__ float sx2r[RROWS];
  __shared__ int   srow[RROWS];
  __shared__ float sd[256];
  __shared__ int   si[256];
  __shared__ int   swin[RROWS];

  const int tid = threadIdx.x;
  int nf = *flag_cnt;
  if (nf > MAXFLAG) nf = MAXFLAG;
  const int base = blockIdx.x * RROWS;
  if (base >= nf) return;
  const int m = (nf - base < RROWS) ? (nf - base) : RROWS;

  if (tid < RROWS) srow[tid] = (tid < m) ? flags[base + tid] : 0;
  __syncthreads();

  // stage flagged rows' x (column gather)
#pragma unroll
  for (int p = 0; p < 2; ++p) {
    int l = p * 4 + (tid >> 6);
    int w = tid & 63;
    if (l < m) {
      int row = srow[l];
      int n2 = row >> 13, t2 = row & (TDIM - 1);
      sxr[l][w] = x[(size_t)n2 * WDIM * TDIM + (size_t)w * TDIM + t2];
    } else if (l < RROWS) {
      sxr[l][w] = 0.f;
    }
  }
  __syncthreads();

  if (tid < RROWS) {   // np-pairwise x2 per row
    const float* sxx = sxr[tid];
    float r8[8];
#pragma unroll
    for (int l = 0; l < 8; ++l) r8[l] = __fmul_rn(sxx[l], sxx[l]);
    for (int i = 8; i < WDIM; i += 8) {
#pragma unroll
      for (int l = 0; l < 8; ++l)
        r8[l] = __fadd_rn(r8[l], __fmul_rn(sxx[i + l], sxx[i + l]));
    }
    sx2r[tid] = __fadd_rn(__fadd_rn(__fadd_rn(r8[0], r8[1]), __fadd_rn(r8[2], r8[3])),
                          __fadd_rn(__fadd_rn(r8[4], r8[5]), __fadd_rn(r8[6], r8[7])));
  }
  __syncthreads();

  float bdv[RROWS];
  int   biv[RROWS];
#pragma unroll
  for (int i = 0; i < RROWS; ++i) { bdv[i] = 3.4e38f; biv[i] = KBINS; }

  for (int c = 0; c < KBINS / 256; ++c) {   // 8 chunks, code = c*256+tid ascending
    const int j = c * 256 + tid;
    const float* kr = kg + (size_t)j * WDIM;
    float acc[RROWS];
#pragma unroll
    for (int i = 0; i < RROWS; ++i) acc[i] = 0.f;
#pragma unroll
    for (int w = 0; w < WDIM; ++w) {
      float kv = kr[w];
#pragma unroll
      for (int i = 0; i < RROWS; ++i)
        acc[i] = __fmaf_rn(sxr[i][w], kv, acc[i]);
    }
    float k2v = k2g[j];
#pragma unroll
    for (int i = 0; i < RROWS; ++i) {
      float d = __fadd_rn(__fsub_rn(sx2r[i], __fmul_rn(2.0f, acc[i])), k2v);
      if (d < bdv[i]) { bdv[i] = d; biv[i] = j; }
    }
  }

  // block-tree argmin per row
  for (int l = 0; l < RROWS; ++l) {
    if (l >= m) break;
    sd[tid] = bdv[l];
    si[tid] = biv[l];
    __syncthreads();
    for (int off = 128; off > 0; off >>= 1) {
      if (tid < off) {
        float od = sd[tid + off];
        int   oi = si[tid + off];
        if (od < sd[tid] || (od == sd[tid] && oi < si[tid])) {
          sd[tid] = od;
          si[tid] = oi;
        }
      }
      __syncthreads();
    }
    if (tid == 0) {
      swin[l] = si[0];
      out[XL_OFF + srow[l]] = (float)si[0];
    }
    __syncthreads();
  }

  // rewrite x_d columns for rechecked rows
#pragma unroll
  for (int p = 0; p < 2; ++p) {
    int l = p * 4 + (tid >> 6);
    int w = tid & 63;
    if (l < m) {
      int row = srow[l];
      int n2 = row >> 13, t2 = row & (TDIM - 1);
      out[XD_OFF + (size_t)n2 * WDIM * TDIM + (size_t)w * TDIM + t2] =
          kg[(size_t)swin[l] * WDIM + w];
    }
  }
}

__global__ void finalize_kernel(const double* __restrict__ wsd, float* __restrict__ out) {
  if (threadIdx.x == 0) {
    double size = (double)XSIZE;
    double commit = wsd[2] / size;
    double fit = wsd[3] / (double)NROWS;
    double mean = wsd[0] / size;
    double var = wsd[1] / size - mean * mean;
    if (var < 0.0) var = 0.0;
    out[SCAL_OFF + 0] = (float)commit;
    out[SCAL_OFF + 1] = (float)fit;
    out[SCAL_OFF + 2] = (float)sqrt(var);
  }
}

extern "C" void kernel_launch(void* const* d_in, const int* in_sizes, int n_in,
                              void* d_out, int out_size, void* d_ws, size_t ws_size,
                              hipStream_t stream) {
  const float* x = (const float*)d_in[0];
  const float* kg = (const float*)d_in[1];
  float* out = (float*)d_out;
  double* wsd = (double*)d_ws;
  float* k2  = (float*)((char*)d_ws + WS_K2_OFF);
  int* cnt   = (int*)((char*)d_ws + WS_CNT_OFF);
  int* flags = (int*)((char*)d_ws + WS_FLAG_OFF);
  short* khi = (short*)((char*)d_ws + WS_KHI_OFF);

  hipLaunchKernelGGL(prep_kernel, dim3(KBINS / 128), dim3(256), 0, stream,
                     kg, k2, khi, wsd, cnt);
  hipLaunchKernelGGL(vq_mfma, dim3(NROWS / MT), dim3(256), 0, stream,
                     x, kg, k2, khi, out, wsd, cnt, flags);
  hipLaunchKernelGGL(recheck_np, dim3(MAXFLAG / RROWS), dim3(256), 0, stream,
                     x, kg, k2, cnt, flags, out);
  hipLaunchKernelGGL(finalize_kernel, dim3(1), dim3(1), 0, stream, wsd, out);
}